// Round 12
// baseline (117.888 us; speedup 1.0000x reference)
//
#include <hip/hip_runtime.h>

// Problem constants: Q=262144, L=512*512, C=128, window 4x4 -> N=16, 4 heads x 32d. B=1.
// ws float layout: [0,2048) ksum (fallback), [2048,4096) vsum (fallback),
//   [4096,5120) k2b: bf16 A-frags, 4 heads x 64 lanes x 16B
//   [5120,7168) v2b: bf16 B-frags, (4 heads x 2 dhalves) x 64 lanes x 16B (keys>=16 zeroed)
//   [6144,8192) fallback k2/v2 f32 (exclusive with main path)
//   [8192,532480) partials p4 (2MB)

typedef __attribute__((ext_vector_type(8))) short bf16x8;
typedef __attribute__((ext_vector_type(4))) float f32x4;
union F4S8 { float4 f; bf16x8 s; };

// ---------------- DPP / swizzle helpers ----------------
template <int CTRL>
__device__ __forceinline__ float dppf(float x) {
    return __int_as_float(
        __builtin_amdgcn_update_dpp(0, __float_as_int(x), CTRL, 0xF, 0xF, true));
}
#define DPP_XOR1 0xB1
#define DPP_XOR2 0x4E
#define DPP_MIR8 0x141

template <int IMM>
__device__ __forceinline__ float swzf(float x) {
    return __int_as_float(__builtin_amdgcn_ds_swizzle(__float_as_int(x), IMM));
}

#define ADD4(A, B) { A.x += B.x; A.y += B.y; A.z += B.z; A.w += B.w; }

#define GLOAD4NT(dst, base, vo) \
    asm volatile("global_load_dwordx4 %0, %1, %2 nt" \
                 : "=v"(dst) : "v"(vo), "s"(base) : "memory")
#define WAITV(n) asm volatile("s_waitcnt vmcnt(" #n ")" ::: "memory")
#define SBAR() __builtin_amdgcn_sched_barrier(0)

__device__ __forceinline__ void gload_lds16(const float4* g, void* l) {
    __builtin_amdgcn_global_load_lds(
        (const __attribute__((address_space(1))) unsigned int*)(const void*)g,
        (__attribute__((address_space(3))) unsigned int*)l, 16, 0, 0);
}

__device__ __forceinline__ unsigned short bf16rne(float x) {
    unsigned u = __float_as_uint(x);
    return (unsigned short)((u + 0x7fffu + ((u >> 16) & 1u)) >> 16);
}
__device__ __forceinline__ unsigned cvtpk_bf16(float lo, float hi) {
    unsigned r;
    asm("v_cvt_pk_bf16_f32 %0, %1, %2" : "=v"(r) : "v"(lo), "v"(hi));
    return r;
}

// ---------------- kernel 1 phase 1: grid-stride NT mean reduction (working) ----
__global__ __launch_bounds__(256, 1) void k_reduce_p1(const float4* __restrict__ k4,
                                                      const float4* __restrict__ v4,
                                                      float4* __restrict__ p4) {
    __shared__ float4 red[256];
    const int t = threadIdx.x;
    const int b = blockIdx.x;          // 0..1023
    const bool isv = (b >= 512);
    const int bb = b & 511;
    const float4* __restrict__ src = isv ? v4 : k4;
    const unsigned vbase = (unsigned)(bb * 256 + t) * 16u;

    float4 a0, a1, a2, a3, a4, a5, a6, a7;
    float4 b0, b1, b2, b3, b4, b5, b6, b7;
    float4 z = make_float4(0.f, 0.f, 0.f, 0.f);
    float4 acc0 = z, acc1 = z, acc2 = z, acc3 = z;

#define OFF(g, i) (vbase + (unsigned)(((g) * 8 + (i)) * 2097152u))
#define ISSUE(G, g) \
    GLOAD4NT(G##0, src, OFF(g, 0)); GLOAD4NT(G##1, src, OFF(g, 1)); \
    GLOAD4NT(G##2, src, OFF(g, 2)); GLOAD4NT(G##3, src, OFF(g, 3)); \
    GLOAD4NT(G##4, src, OFF(g, 4)); GLOAD4NT(G##5, src, OFF(g, 5)); \
    GLOAD4NT(G##6, src, OFF(g, 6)); GLOAD4NT(G##7, src, OFF(g, 7))
#define CONSUME_A() \
    ADD4(acc0, a0); ADD4(acc1, a1); ADD4(acc2, a2); ADD4(acc3, a3); \
    ADD4(acc0, a4); ADD4(acc1, a5); ADD4(acc2, a6); ADD4(acc3, a7)
#define CONSUME_B() \
    ADD4(acc0, b0); ADD4(acc1, b1); ADD4(acc2, b2); ADD4(acc3, b3); \
    ADD4(acc0, b4); ADD4(acc1, b5); ADD4(acc2, b6); ADD4(acc3, b7)

    ISSUE(a, 0);  ISSUE(b, 1);
    WAITV(8); SBAR(); CONSUME_A(); ISSUE(a, 2);
    WAITV(8); SBAR(); CONSUME_B(); ISSUE(b, 3);
    WAITV(8); SBAR(); CONSUME_A(); ISSUE(a, 4);
    WAITV(8); SBAR(); CONSUME_B(); ISSUE(b, 5);
    WAITV(8); SBAR(); CONSUME_A(); ISSUE(a, 6);
    WAITV(8); SBAR(); CONSUME_B(); ISSUE(b, 7);
    WAITV(8); SBAR(); CONSUME_A();
    WAITV(0); SBAR(); CONSUME_B();

    ADD4(acc0, acc1);
    ADD4(acc2, acc3);
    ADD4(acc0, acc2);
    red[t] = acc0;
    __syncthreads();

    if (t < 128) {
        float4 s = red[t];
        const float4 p = red[t + 128];
        ADD4(s, p);
        p4[(isv ? 65536 : 0) + bb * 128 + t] = s;
    }
}

// ---------------- kernel 1 phase 2: partials -> packed bf16 MFMA fragments ----
__global__ __launch_bounds__(256) void k_finish(const float4* __restrict__ p4,
                                                const float* __restrict__ logit_scale,
                                                float4* __restrict__ k2bf4,
                                                float* __restrict__ v2b_base) {
    __shared__ float4 lsum[256];
    __shared__ unsigned short kb16[128];
    __shared__ float vb32[128];
    const int b = blockIdx.x;
    const int srcv = b >> 4;
    const int rc = (b >> 2) & 3;
    const int cc = b & 3;
    const int n = rc * 4 + cc;
    const int t = threadIdx.x;
    const int w0 = t >> 5;
    const int q = t & 31;

    const float4* base = p4 + srcv * 65536 + cc * 32 + q;
    float4 s = make_float4(0.f, 0.f, 0.f, 0.f);
#pragma unroll
    for (int b1 = 0; b1 < 2; ++b1) {
#pragma unroll
        for (int j = 0; j < 8; ++j) {
            const int bb = b1 * 256 + rc * 64 + w0 * 8 + j;
            const float4 x = base[bb * 128];
            ADD4(s, x);
        }
    }
    lsum[t] = s;
    __syncthreads();

    if (t < 32) {
        float4 m = lsum[t];
#pragma unroll
        for (int w = 1; w < 8; ++w) {
            const float4 x = lsum[w * 32 + t];
            ADD4(m, x);
        }
        const float inv = 1.0f / 16384.0f;
        m.x *= inv; m.y *= inv; m.z *= inv; m.w *= inv;

        if (srcv == 0) {
            const int h = t >> 3;        // head of this channel-quad
            float ss = m.x * m.x + m.y * m.y + m.z * m.z + m.w * m.w;
            ss += dppf<DPP_XOR1>(ss);
            ss += dppf<DPP_XOR2>(ss);
            ss += dppf<DPP_MIR8>(ss);    // per-head sum over its 8 lanes
            const float sc = __expf(fminf(logit_scale[h], 4.6051702f)); // log(1/0.01)
            const float f = sc / fmaxf(sqrtf(ss), 1e-12f);
            kb16[4 * t + 0] = bf16rne(m.x * f);
            kb16[4 * t + 1] = bf16rne(m.y * f);
            kb16[4 * t + 2] = bf16rne(m.z * f);
            kb16[4 * t + 3] = bf16rne(m.w * f);
        } else {
            vb32[4 * t + 0] = m.x;
            vb32[4 * t + 1] = m.y;
            vb32[4 * t + 2] = m.z;
            vb32[4 * t + 3] = m.w;
        }
    }
    __syncthreads();

    if (srcv == 0) {
        if (t < 16) {
            const int h = t >> 2, lg = t & 3;
            const uint4* kb4 = (const uint4*)kb16;   // 8 ushorts per uint4
            const uint4 rec = kb4[h * 4 + lg];       // channels h*32+lg*8 .. +7
            k2bf4[h * 64 + n + lg * 16] = make_float4(
                __uint_as_float(rec.x), __uint_as_float(rec.y),
                __uint_as_float(rec.z), __uint_as_float(rec.w));
        }
    } else {
        unsigned short* v2u16 = (unsigned short*)v2b_base;
        unsigned* v2u32 = (unsigned*)v2b_base;
        if (t < 128) {
            const int h = t >> 5, hf = (t >> 4) & 1, d = t & 15;
            const int l = (n >> 3) * 16 + d;
            const int j = n & 7;
            v2u16[((h * 2 + hf) * 64 + l) * 8 + j] = bf16rne(vb32[h * 32 + hf * 16 + d]);
        }
        if (t < 64) {   // zero-fill lanes 32..63 (keys 16..31)
            const int gi = n * 64 + t;           // 0..1023
            const int fg = gi >> 7;              // frag group 0..7
            const int rem = gi & 127;
            const int l2 = 32 + (rem >> 2);
            const int c = rem & 3;
            v2u32[(fg * 64 + l2) * 4 + c] = 0u;
        }
    }
}

// ---------------- kernel 2: MFMA attention (R10 config, cached q/mask) ----------
// R12 single lever vs R10: out stores CACHED (plain) instead of nt. Out is
// rewritten in place every replay and only read at validation; cached stores
// let L2/L3 absorb the 128MB and defer HBM writeback to eviction. Paired
// olo/ohi stores cover each 128B line fully -> L2 write-combining, no RMW.
// q/mask stay cached (R11 proved L3 retains ~half of q across replays;
// nt q-loads cost +15.7us). k/v reads stay nt in p1 (no L3 pollution).
__global__ __launch_bounds__(256) void k_attn_mfma(const float4* __restrict__ q4,
                                                   const float4* __restrict__ mask4,
                                                   const float4* __restrict__ k2b,
                                                   const float4* __restrict__ v2b,
                                                   float* __restrict__ outp) {
    const int tid = threadIdx.x;
    const int l = tid & 63, wv = tid >> 6;
    const int gw = blockIdx.x * 4 + wv;          // 0..16383
    const int ql = l & 15, g4 = l >> 4;
    const int qq = gw * 16 + ql;

    // K2 A-frags + V B-frags (L2-hot, 12KB shared by all waves)
    F4S8 kb[4];
    F4S8 vb[8];
#pragma unroll
    for (int h = 0; h < 4; ++h) kb[h].f = k2b[h * 64 + l];
#pragma unroll
    for (int i = 0; i < 8; ++i) vb[i].f = v2b[i * 64 + l];

    // Q fp32: per head dims g4*8 .. +7 (two float4)
    float4 qa[4], qb[4];
#pragma unroll
    for (int h = 0; h < 4; ++h) {
        qa[h] = q4[qq * 32 + h * 8 + g4 * 2];
        qb[h] = q4[qq * 32 + h * 8 + g4 * 2 + 1];
    }
    const float4 mk = mask4[qq * 4 + g4];        // mask[qq][g4*4 .. +3]

    const f32x4 z4 = {0.f, 0.f, 0.f, 0.f};
    const int src0 = ql + g4 * 32;               // P-gather source lanes
    const int src1 = src0 + 16;

#pragma unroll
    for (int h = 0; h < 4; ++h) {
        // ---- q norm over the 32-dim head ----
        float ss = qa[h].x * qa[h].x + qa[h].y * qa[h].y + qa[h].z * qa[h].z + qa[h].w * qa[h].w
                 + qb[h].x * qb[h].x + qb[h].y * qb[h].y + qb[h].z * qb[h].z + qb[h].w * qb[h].w;
        ss += __shfl_xor(ss, 16, 64);
        ss += __shfl_xor(ss, 32, 64);
        const float rn = rsqrtf(fmaxf(ss, 1e-24f));

        // ---- pack qhat to bf16x8 B-frag ----
        F4S8 af;
        af.f = make_float4(
            __uint_as_float(cvtpk_bf16(qa[h].x * rn, qa[h].y * rn)),
            __uint_as_float(cvtpk_bf16(qa[h].z * rn, qa[h].w * rn)),
            __uint_as_float(cvtpk_bf16(qb[h].x * rn, qb[h].y * rn)),
            __uint_as_float(cvtpk_bf16(qb[h].z * rn, qb[h].w * rn)));

        // ---- S^T = K2 . Qhat^T ----
        f32x4 st = __builtin_amdgcn_mfma_f32_16x16x32_bf16(kb[h].s, af.s, z4, 0, 0, 0);

        // ---- softmax (lane holds keys g4*4+r of query ql) ----
        const float e0 = __expf(st[0] + mk.x);
        const float e1 = __expf(st[1] + mk.y);
        const float e2 = __expf(st[2] + mk.z);
        const float e3 = __expf(st[3] + mk.w);
        float ds = (e0 + e1) + (e2 + e3);
        ds += __shfl_xor(ds, 16, 64);
        ds += __shfl_xor(ds, 32, 64);
        const float rden = 1.0f / ds;

        const unsigned a01 = cvtpk_bf16(e0 * rden, e1 * rden);
        const unsigned a23 = cvtpk_bf16(e2 * rden, e3 * rden);

        // ---- gather P into K=32 A-frag (keys>=16 garbage annihilated by V zeros) ----
        const unsigned u0 = (unsigned)__shfl((int)a01, src0 & 63, 64);
        const unsigned u1 = (unsigned)__shfl((int)a23, src0 & 63, 64);
        const unsigned u2 = (unsigned)__shfl((int)a01, src1 & 63, 64);
        const unsigned u3 = (unsigned)__shfl((int)a23, src1 & 63, 64);
        F4S8 pa;
        pa.f = make_float4(__uint_as_float(u0), __uint_as_float(u1),
                           __uint_as_float(u2), __uint_as_float(u3));

        // ---- O = P . V  (two d-halves) ----
        f32x4 olo = __builtin_amdgcn_mfma_f32_16x16x32_bf16(pa.s, vb[h * 2 + 0].s, z4, 0, 0, 0);
        f32x4 ohi = __builtin_amdgcn_mfma_f32_16x16x32_bf16(pa.s, vb[h * 2 + 1].s, z4, 0, 0, 0);

        // ---- store: lane holds O[q=gw*16+g4*4+r][d=hf*16+ql] of head h (cached) ----
        float* ob = outp + (size_t)(gw * 16 + g4 * 4) * 128 + h * 32 + ql;
#pragma unroll
        for (int r = 0; r < 4; ++r) {
            ob[r * 128] = olo[r];
            ob[r * 128 + 16] = ohi[r];
        }
    }
}

// ---------------- fallback (ws too small): atomic + prep + f32 attn ----------------
__global__ __launch_bounds__(256) void k_reduce_atomic(const float4* __restrict__ k4,
                                                       const float4* __restrict__ v4,
                                                       float* __restrict__ ksum,
                                                       float* __restrict__ vsum) {
    __shared__ float4 stage[2048];
    __shared__ float4 redE[256];
    __shared__ float4 redO[256];
    const int t = threadIdx.x;
    const int b = blockIdx.x;
    const bool isv = (b >= 1024);
    const int bb = b & 1023;
    const float4* __restrict__ src = isv ? v4 : k4;
    float* __restrict__ dst = isv ? vsum : ksum;

    const int wv = t >> 6;
    const int ln = t & 63;
    const long gstart = (long)bb * 8192 + wv * 2048;
    const float4* gsrc = src + gstart + ln;
    char* lbase = (char*)stage + wv * 8192;

#pragma unroll
    for (int j = 0; j < 4; ++j)
        gload_lds16(gsrc + j * 64, lbase + j * 1024);

    float4 z = make_float4(0.f, 0.f, 0.f, 0.f);
    float4 accE = z, accO = z;

#pragma unroll
    for (int c = 0; c < 8; ++c) {
        if (c < 7) {
            const int p1 = (c + 1) & 1;
#pragma unroll
            for (int j = 0; j < 4; ++j)
                gload_lds16(gsrc + (c + 1) * 256 + j * 64,
                            lbase + p1 * 4096 + j * 1024);
            asm volatile("s_waitcnt vmcnt(4)" ::: "memory");
        } else {
            asm volatile("s_waitcnt vmcnt(0)" ::: "memory");
        }
        __builtin_amdgcn_sched_barrier(0);
        const int p = c & 1;
        const float4* lf = (const float4*)(lbase + p * 4096) + ln;
        const float4 x0 = lf[0];
        const float4 x1 = lf[64];
        const float4 x2 = lf[128];
        const float4 x3 = lf[192];
        ADD4(accE, x0); ADD4(accO, x1); ADD4(accE, x2); ADD4(accO, x3);
    }

    redE[wv * 64 + ln] = accE;
    redO[wv * 64 + ln] = accO;
    __syncthreads();

    if (t < 128) {
        const int n0 = t >> 5;
        const int c4 = t & 31;
        const float4* arr = (n0 < 2) ? redE : redO;
        const int base = (n0 & 1) * 32 + c4;
        float4 s = arr[base];
        const float4 s1 = arr[base + 64];
        const float4 s2 = arr[base + 128];
        const float4 s3 = arr[base + 192];
        ADD4(s, s1); ADD4(s, s2); ADD4(s, s3);
        const int n = ((bb >> 1) & 3) * 4 + n0;
        const int c = c4 * 4;
        atomicAdd(&dst[n * 128 + c + 0], s.x);
        atomicAdd(&dst[n * 128 + c + 1], s.y);
        atomicAdd(&dst[n * 128 + c + 2], s.z);
        atomicAdd(&dst[n * 128 + c + 3], s.w);
    }
}

__global__ __launch_bounds__(256) void k_prep(const float* __restrict__ ksum,
                                              const float* __restrict__ vsum,
                                              const float* __restrict__ logit_scale,
                                              float* __restrict__ k2,
                                              float* __restrict__ v2) {
    __shared__ float mk[2048], mv[2048], fac[64];
    const int t = threadIdx.x;
    const float inv = 1.0f / 16384.0f;
    for (int w = t; w < 2048; w += 256) {
        mk[w] = ksum[w] * inv;
        mv[w] = vsum[w] * inv;
    }
    __syncthreads();
    if (t < 64) {
        const int h = t >> 4, n = t & 15;
        float ss = 0.f;
#pragma unroll
        for (int d = 0; d < 32; ++d) {
            float x = mk[n * 128 + h * 32 + d];
            ss += x * x;
        }
        const float nrm = sqrtf(ss);
        const float sc = __expf(fminf(logit_scale[h], 4.6051702f));
        fac[t] = sc / fmaxf(nrm, 1e-12f);
    }
    __syncthreads();
    for (int w = t; w < 2048; w += 256) {
        const int h = w >> 9;
        const int n = (w & 511) >> 5;
        const int d = w & 31;
        const float f = fac[h * 16 + n];
        k2[w] = mk[n * 128 + h * 32 + d] * f;
        v2[w] = mv[n * 128 + h * 32 + d];
    }
}

__global__ __launch_bounds__(256, 2) void k_attn(const float4* __restrict__ q4,
                                                 const float2* __restrict__ mask2,
                                                 const float4* __restrict__ k2f4,
                                                 const float4* __restrict__ v2f4,
                                                 float4* __restrict__ out4) {
    const int t = threadIdx.x;
    const int isub = t >> 5;
    const int l5 = t & 31;
    const int h = l5 >> 3;
    const int g = l5 & 7;

    float4 kreg[16], vreg[16];
#pragma unroll
    for (int n = 0; n < 16; ++n) {
        kreg[n] = k2f4[h * 128 + n * 8 + g];
        vreg[n] = v2f4[h * 128 + n * 8 + g];
    }

    const bool b2 = (g & 4) != 0;
    const bool b1 = (g & 2) != 0;
    const bool b0 = (g & 1) != 0;

    auto process = [&](const float4 qv, const float2 mw) -> float4 {
        float ss = qv.x * qv.x + qv.y * qv.y + qv.z * qv.z + qv.w * qv.w;
        ss += dppf<DPP_XOR1>(ss);
        ss += dppf<DPP_XOR2>(ss);
        ss += dppf<DPP_MIR8>(ss);
        const float rn = rsqrtf(fmaxf(ss, 1e-24f));
        const float qx = qv.x * rn, qy = qv.y * rn, qz = qv.z * rn, qw = qv.w * rn;

        float part[16];
#pragma unroll
        for (int n = 0; n < 16; ++n)
            part[n] = qx * kreg[n].x + qy * kreg[n].y + qz * kreg[n].z + qw * kreg[n].w;

        float r8[8];
#pragma unroll
        for (int j = 0; j < 8; ++j) {
            const float snd = b2 ? part[j] : part[j + 8];
            const float kp  = b2 ? part[j + 8] : part[j];
            r8[j] = kp + dppf<DPP_MIR8>(snd);
        }
        float r4[4];
#pragma unroll
        for (int j = 0; j < 4; ++j) {
            const float snd = b1 ? r8[j] : r8[j + 4];
            const float kp  = b1 ? r8[j + 4] : r8[j];
            r4[j] = kp + dppf<DPP_XOR2>(snd);
        }
        float s0, s1;
        {
            const float sndA = b0 ? r4[0] : r4[2];
            const float kpA  = b0 ? r4[2] : r4[0];
            s0 = kpA + dppf<DPP_XOR1>(sndA);
            const float sndB = b0 ? r4[1] : r4[3];
            const float kpB  = b0 ? r4[3] : r4[1];
            s1 = kpB + dppf<DPP_XOR1>(sndB);
        }

        const float e0 = __expf(s0 + mw.x);
        const float e1 = __expf(s1 + mw.y);

        float ds = e0 + e1;
        ds += dppf<DPP_XOR1>(ds);
        ds += dppf<DPP_XOR2>(ds);
        ds += dppf<DPP_MIR8>(ds);
        const float rden = 1.0f / ds;

        float pf[16];
        pf[0]  = swzf<(0 << 5) | 0x18>(e0);
        pf[1]  = swzf<(0 << 5) | 0x18>(e1);
        pf[2]  = swzf<(1 << 5) | 0x18>(e0);
        pf[3]  = swzf<(1 << 5) | 0x18>(e1);
        pf[4]  = swzf<(2 << 5) | 0x18>(e0);
        pf[5]  = swzf<(2 << 5) | 0x18>(e1);
        pf[6]  = swzf<(3 << 5) | 0x18>(e0);
        pf[7]  = swzf<(3 << 5) | 0x18>(e1);
        pf[8]  = swzf<(4 << 5) | 0x18>(e0);
        pf[9]  = swzf<(4 << 5) | 0x18>(e1);
        pf[10] = swzf<(5 << 5) | 0x18>(e0);
        pf[11] = swzf<(5 << 5) | 0x18>(e1);
        pf[12] = swzf<(6 << 5) | 0x18>(e0);
        pf[13] = swzf<(6 << 5) | 0x18>(e1);
        pf[14] = swzf<(7 << 5) | 0x18>(e0);
        pf[15] = swzf<(7 << 5) | 0x18>(e1);

        float ox = 0.f, oy = 0.f, oz = 0.f, ow = 0.f;
#pragma unroll
        for (int n = 0; n < 16; ++n) {
            ox += pf[n] * vreg[n].x;
            oy += pf[n] * vreg[n].y;
            oz += pf[n] * vreg[n].z;
            ow += pf[n] * vreg[n].w;
        }
        return make_float4(ox * rden, oy * rden, oz * rden, ow * rden);
    };

    int i = blockIdx.x * 128 + isub;
    float4 qA = q4[i * 32 + h * 8 + g];
    float4 qB = q4[(i + 8) * 32 + h * 8 + g];
    float2 mA = mask2[i * 8 + g];
    float2 mB = mask2[(i + 8) * 8 + g];

#pragma unroll 1
    for (int iter = 0; iter < 8; ++iter) {
        const int ip = (iter < 7) ? (i + 16) : i;
        const float4 qA_n = q4[ip * 32 + h * 8 + g];
        const float4 qB_n = q4[(ip + 8) * 32 + h * 8 + g];
        const float2 mA_n = mask2[ip * 8 + g];
        const float2 mB_n = mask2[(ip + 8) * 8 + g];

        const float4 oA = process(qA, mA);
        const float4 oB = process(qB, mB);
        out4[i * 32 + h * 8 + g] = oA;
        out4[(i + 8) * 32 + h * 8 + g] = oB;

        i += 16;
        qA = qA_n; qB = qB_n; mA = mA_n; mB = mB_n;
    }
}

extern "C" void kernel_launch(void* const* d_in, const int* in_sizes, int n_in,
                              void* d_out, int out_size, void* d_ws, size_t ws_size,
                              hipStream_t stream) {
    (void)in_sizes; (void)n_in; (void)out_size;
    const float* q = (const float*)d_in[0];
    const float* k = (const float*)d_in[1];
    const float* v = (const float*)d_in[2];
    const float* mask = (const float*)d_in[5];
    const float* ls = (const float*)d_in[6];

    float* ws = (float*)d_ws;
    float* ksum = ws;
    float* vsum = ws + 2048;
    float* k2b = ws + 4096;    // 1024 floats: packed K2 A-frags
    float* v2b = ws + 5120;    // 2048 floats: packed V B-frags
    float* k2 = ws + 4096;     // fallback f32 (exclusive path)
    float* v2 = ws + 6144;     // fallback f32
    float* part = ws + 8192;   // 131072 float4 = 2MB

    const size_t needed = (size_t)8192 * 4 + (size_t)131072 * 16;
    if (ws_size >= needed) {
        k_reduce_p1<<<1024, 256, 0, stream>>>((const float4*)k, (const float4*)v,
                                              (float4*)part);
        k_finish<<<32, 256, 0, stream>>>((const float4*)part, ls,
                                         (float4*)k2b, v2b);
        k_attn_mfma<<<4096, 256, 0, stream>>>((const float4*)q, (const float4*)mask,
                                              (const float4*)k2b, (const float4*)v2b,
                                              (float*)d_out);
    } else {
        hipMemsetAsync(ws, 0, 4096 * sizeof(float), stream);
        k_reduce_atomic<<<2048, 256, 0, stream>>>((const float4*)k, (const float4*)v,
                                                  ksum, vsum);
        k_prep<<<1, 256, 0, stream>>>(ksum, vsum, ls, k2, v2);
        k_attn<<<2048, 256, 0, stream>>>((const float4*)q, (const float2*)mask,
                                         (const float4*)k2, (const float4*)v2,
                                         (float4*)d_out);
    }
}

// Round 13
// 98.882 us; speedup vs baseline: 1.1922x; 1.1922x over previous
//
#include <hip/hip_runtime.h>

// Problem constants: Q=262144, L=512*512, C=128, window 4x4 -> N=16, 4 heads x 32d. B=1.
// ws float layout: [0,2048) ksum (fallback), [2048,4096) vsum (fallback),
//   [4096,5120) k2b: bf16 A-frags, 4 heads x 64 lanes x 16B
//   [5120,7168) v2b: bf16 B-frags, (4 heads x 2 dhalves) x 64 lanes x 16B (keys>=16 zeroed)
//   [6144,8192) fallback k2/v2 f32 (exclusive with main path)
//   [8192,532480) partials p4 (2MB)
//
// FINAL CONFIG (R10, empirical optimum of the cache-policy space):
//   - p1 k/v reads: NT (asm global_load_dwordx4 nt) -- broke the ~2.8 TB/s
//     cached-read wall (R1-R8), no L3 pollution of q.
//   - attn q/mask reads: CACHED -- L3 retains ~half of q across replays
//     (R11: nt q-loads +15.7us).
//   - attn out stores: NT -- cached stores add dirty-writeback pressure
//     (R12: +18.3us).
//   - attention on MFMA (R10: VALU-bound 90us -> memory-bound ~40us).

typedef __attribute__((ext_vector_type(8))) short bf16x8;
typedef __attribute__((ext_vector_type(4))) float f32x4;
union F4S8 { float4 f; bf16x8 s; };

// ---------------- DPP / swizzle helpers ----------------
template <int CTRL>
__device__ __forceinline__ float dppf(float x) {
    return __int_as_float(
        __builtin_amdgcn_update_dpp(0, __float_as_int(x), CTRL, 0xF, 0xF, true));
}
#define DPP_XOR1 0xB1
#define DPP_XOR2 0x4E
#define DPP_MIR8 0x141

template <int IMM>
__device__ __forceinline__ float swzf(float x) {
    return __int_as_float(__builtin_amdgcn_ds_swizzle(__float_as_int(x), IMM));
}

#define ADD4(A, B) { A.x += B.x; A.y += B.y; A.z += B.z; A.w += B.w; }

#define GLOAD4NT(dst, base, vo) \
    asm volatile("global_load_dwordx4 %0, %1, %2 nt" \
                 : "=v"(dst) : "v"(vo), "s"(base) : "memory")
#define WAITV(n) asm volatile("s_waitcnt vmcnt(" #n ")" ::: "memory")
#define SBAR() __builtin_amdgcn_sched_barrier(0)

__device__ __forceinline__ void gload_lds16(const float4* g, void* l) {
    __builtin_amdgcn_global_load_lds(
        (const __attribute__((address_space(1))) unsigned int*)(const void*)g,
        (__attribute__((address_space(3))) unsigned int*)l, 16, 0, 0);
}

__device__ __forceinline__ unsigned short bf16rne(float x) {
    unsigned u = __float_as_uint(x);
    return (unsigned short)((u + 0x7fffu + ((u >> 16) & 1u)) >> 16);
}
__device__ __forceinline__ unsigned cvtpk_bf16(float lo, float hi) {
    unsigned r;
    asm("v_cvt_pk_bf16_f32 %0, %1, %2" : "=v"(r) : "v"(lo), "v"(hi));
    return r;
}

// ---------------- kernel 1 phase 1: grid-stride NT mean reduction ----------------
__global__ __launch_bounds__(256, 1) void k_reduce_p1(const float4* __restrict__ k4,
                                                      const float4* __restrict__ v4,
                                                      float4* __restrict__ p4) {
    __shared__ float4 red[256];
    const int t = threadIdx.x;
    const int b = blockIdx.x;          // 0..1023
    const bool isv = (b >= 512);
    const int bb = b & 511;
    const float4* __restrict__ src = isv ? v4 : k4;
    const unsigned vbase = (unsigned)(bb * 256 + t) * 16u;

    float4 a0, a1, a2, a3, a4, a5, a6, a7;
    float4 b0, b1, b2, b3, b4, b5, b6, b7;
    float4 z = make_float4(0.f, 0.f, 0.f, 0.f);
    float4 acc0 = z, acc1 = z, acc2 = z, acc3 = z;

#define OFF(g, i) (vbase + (unsigned)(((g) * 8 + (i)) * 2097152u))
#define ISSUE(G, g) \
    GLOAD4NT(G##0, src, OFF(g, 0)); GLOAD4NT(G##1, src, OFF(g, 1)); \
    GLOAD4NT(G##2, src, OFF(g, 2)); GLOAD4NT(G##3, src, OFF(g, 3)); \
    GLOAD4NT(G##4, src, OFF(g, 4)); GLOAD4NT(G##5, src, OFF(g, 5)); \
    GLOAD4NT(G##6, src, OFF(g, 6)); GLOAD4NT(G##7, src, OFF(g, 7))
#define CONSUME_A() \
    ADD4(acc0, a0); ADD4(acc1, a1); ADD4(acc2, a2); ADD4(acc3, a3); \
    ADD4(acc0, a4); ADD4(acc1, a5); ADD4(acc2, a6); ADD4(acc3, a7)
#define CONSUME_B() \
    ADD4(acc0, b0); ADD4(acc1, b1); ADD4(acc2, b2); ADD4(acc3, b3); \
    ADD4(acc0, b4); ADD4(acc1, b5); ADD4(acc2, b6); ADD4(acc3, b7)

    ISSUE(a, 0);  ISSUE(b, 1);
    WAITV(8); SBAR(); CONSUME_A(); ISSUE(a, 2);
    WAITV(8); SBAR(); CONSUME_B(); ISSUE(b, 3);
    WAITV(8); SBAR(); CONSUME_A(); ISSUE(a, 4);
    WAITV(8); SBAR(); CONSUME_B(); ISSUE(b, 5);
    WAITV(8); SBAR(); CONSUME_A(); ISSUE(a, 6);
    WAITV(8); SBAR(); CONSUME_B(); ISSUE(b, 7);
    WAITV(8); SBAR(); CONSUME_A();
    WAITV(0); SBAR(); CONSUME_B();

    ADD4(acc0, acc1);
    ADD4(acc2, acc3);
    ADD4(acc0, acc2);
    red[t] = acc0;
    __syncthreads();

    if (t < 128) {
        float4 s = red[t];
        const float4 p = red[t + 128];
        ADD4(s, p);
        p4[(isv ? 65536 : 0) + bb * 128 + t] = s;
    }
}

// ---------------- kernel 1 phase 2: partials -> packed bf16 MFMA fragments ----
__global__ __launch_bounds__(256) void k_finish(const float4* __restrict__ p4,
                                                const float* __restrict__ logit_scale,
                                                float4* __restrict__ k2bf4,
                                                float* __restrict__ v2b_base) {
    __shared__ float4 lsum[256];
    __shared__ unsigned short kb16[128];
    __shared__ float vb32[128];
    const int b = blockIdx.x;
    const int srcv = b >> 4;
    const int rc = (b >> 2) & 3;
    const int cc = b & 3;
    const int n = rc * 4 + cc;
    const int t = threadIdx.x;
    const int w0 = t >> 5;
    const int q = t & 31;

    const float4* base = p4 + srcv * 65536 + cc * 32 + q;
    float4 s = make_float4(0.f, 0.f, 0.f, 0.f);
#pragma unroll
    for (int b1 = 0; b1 < 2; ++b1) {
#pragma unroll
        for (int j = 0; j < 8; ++j) {
            const int bb = b1 * 256 + rc * 64 + w0 * 8 + j;
            const float4 x = base[bb * 128];
            ADD4(s, x);
        }
    }
    lsum[t] = s;
    __syncthreads();

    if (t < 32) {
        float4 m = lsum[t];
#pragma unroll
        for (int w = 1; w < 8; ++w) {
            const float4 x = lsum[w * 32 + t];
            ADD4(m, x);
        }
        const float inv = 1.0f / 16384.0f;
        m.x *= inv; m.y *= inv; m.z *= inv; m.w *= inv;

        if (srcv == 0) {
            const int h = t >> 3;        // head of this channel-quad
            float ss = m.x * m.x + m.y * m.y + m.z * m.z + m.w * m.w;
            ss += dppf<DPP_XOR1>(ss);
            ss += dppf<DPP_XOR2>(ss);
            ss += dppf<DPP_MIR8>(ss);    // per-head sum over its 8 lanes
            const float sc = __expf(fminf(logit_scale[h], 4.6051702f)); // log(1/0.01)
            const float f = sc / fmaxf(sqrtf(ss), 1e-12f);
            kb16[4 * t + 0] = bf16rne(m.x * f);
            kb16[4 * t + 1] = bf16rne(m.y * f);
            kb16[4 * t + 2] = bf16rne(m.z * f);
            kb16[4 * t + 3] = bf16rne(m.w * f);
        } else {
            vb32[4 * t + 0] = m.x;
            vb32[4 * t + 1] = m.y;
            vb32[4 * t + 2] = m.z;
            vb32[4 * t + 3] = m.w;
        }
    }
    __syncthreads();

    if (srcv == 0) {
        if (t < 16) {
            const int h = t >> 2, lg = t & 3;
            const uint4* kb4 = (const uint4*)kb16;   // 8 ushorts per uint4
            const uint4 rec = kb4[h * 4 + lg];       // channels h*32+lg*8 .. +7
            k2bf4[h * 64 + n + lg * 16] = make_float4(
                __uint_as_float(rec.x), __uint_as_float(rec.y),
                __uint_as_float(rec.z), __uint_as_float(rec.w));
        }
    } else {
        unsigned short* v2u16 = (unsigned short*)v2b_base;
        unsigned* v2u32 = (unsigned*)v2b_base;
        if (t < 128) {
            const int h = t >> 5, hf = (t >> 4) & 1, d = t & 15;
            const int l = (n >> 3) * 16 + d;
            const int j = n & 7;
            v2u16[((h * 2 + hf) * 64 + l) * 8 + j] = bf16rne(vb32[h * 32 + hf * 16 + d]);
        }
        if (t < 64) {   // zero-fill lanes 32..63 (keys 16..31)
            const int gi = n * 64 + t;           // 0..1023
            const int fg = gi >> 7;              // frag group 0..7
            const int rem = gi & 127;
            const int l2 = 32 + (rem >> 2);
            const int c = rem & 3;
            v2u32[(fg * 64 + l2) * 4 + c] = 0u;
        }
    }
}

// ---------------- kernel 2: MFMA attention (cached q/mask, NT out) ----------------
__global__ __launch_bounds__(256) void k_attn_mfma(const float4* __restrict__ q4,
                                                   const float4* __restrict__ mask4,
                                                   const float4* __restrict__ k2b,
                                                   const float4* __restrict__ v2b,
                                                   float* __restrict__ outp) {
    const int tid = threadIdx.x;
    const int l = tid & 63, wv = tid >> 6;
    const int gw = blockIdx.x * 4 + wv;          // 0..16383
    const int ql = l & 15, g4 = l >> 4;
    const int qq = gw * 16 + ql;

    // K2 A-frags + V B-frags (L2-hot, 12KB shared by all waves)
    F4S8 kb[4];
    F4S8 vb[8];
#pragma unroll
    for (int h = 0; h < 4; ++h) kb[h].f = k2b[h * 64 + l];
#pragma unroll
    for (int i = 0; i < 8; ++i) vb[i].f = v2b[i * 64 + l];

    // Q fp32: per head dims g4*8 .. +7 (two float4)
    float4 qa[4], qb[4];
#pragma unroll
    for (int h = 0; h < 4; ++h) {
        qa[h] = q4[qq * 32 + h * 8 + g4 * 2];
        qb[h] = q4[qq * 32 + h * 8 + g4 * 2 + 1];
    }
    const float4 mk = mask4[qq * 4 + g4];        // mask[qq][g4*4 .. +3]

    const f32x4 z4 = {0.f, 0.f, 0.f, 0.f};
    const int src0 = ql + g4 * 32;               // P-gather source lanes
    const int src1 = src0 + 16;

#pragma unroll
    for (int h = 0; h < 4; ++h) {
        // ---- q norm over the 32-dim head ----
        float ss = qa[h].x * qa[h].x + qa[h].y * qa[h].y + qa[h].z * qa[h].z + qa[h].w * qa[h].w
                 + qb[h].x * qb[h].x + qb[h].y * qb[h].y + qb[h].z * qb[h].z + qb[h].w * qb[h].w;
        ss += __shfl_xor(ss, 16, 64);
        ss += __shfl_xor(ss, 32, 64);
        const float rn = rsqrtf(fmaxf(ss, 1e-24f));

        // ---- pack qhat to bf16x8 B-frag ----
        F4S8 af;
        af.f = make_float4(
            __uint_as_float(cvtpk_bf16(qa[h].x * rn, qa[h].y * rn)),
            __uint_as_float(cvtpk_bf16(qa[h].z * rn, qa[h].w * rn)),
            __uint_as_float(cvtpk_bf16(qb[h].x * rn, qb[h].y * rn)),
            __uint_as_float(cvtpk_bf16(qb[h].z * rn, qb[h].w * rn)));

        // ---- S^T = K2 . Qhat^T ----
        f32x4 st = __builtin_amdgcn_mfma_f32_16x16x32_bf16(kb[h].s, af.s, z4, 0, 0, 0);

        // ---- softmax (lane holds keys g4*4+r of query ql) ----
        const float e0 = __expf(st[0] + mk.x);
        const float e1 = __expf(st[1] + mk.y);
        const float e2 = __expf(st[2] + mk.z);
        const float e3 = __expf(st[3] + mk.w);
        float ds = (e0 + e1) + (e2 + e3);
        ds += __shfl_xor(ds, 16, 64);
        ds += __shfl_xor(ds, 32, 64);
        const float rden = 1.0f / ds;

        const unsigned a01 = cvtpk_bf16(e0 * rden, e1 * rden);
        const unsigned a23 = cvtpk_bf16(e2 * rden, e3 * rden);

        // ---- gather P into K=32 A-frag (keys>=16 garbage annihilated by V zeros) ----
        const unsigned u0 = (unsigned)__shfl((int)a01, src0 & 63, 64);
        const unsigned u1 = (unsigned)__shfl((int)a23, src0 & 63, 64);
        const unsigned u2 = (unsigned)__shfl((int)a01, src1 & 63, 64);
        const unsigned u3 = (unsigned)__shfl((int)a23, src1 & 63, 64);
        F4S8 pa;
        pa.f = make_float4(__uint_as_float(u0), __uint_as_float(u1),
                           __uint_as_float(u2), __uint_as_float(u3));

        // ---- O = P . V  (two d-halves) ----
        f32x4 olo = __builtin_amdgcn_mfma_f32_16x16x32_bf16(pa.s, vb[h * 2 + 0].s, z4, 0, 0, 0);
        f32x4 ohi = __builtin_amdgcn_mfma_f32_16x16x32_bf16(pa.s, vb[h * 2 + 1].s, z4, 0, 0, 0);

        // ---- store: lane holds O[q=gw*16+g4*4+r][d=hf*16+ql] of head h (nt) ----
        float* ob = outp + (size_t)(gw * 16 + g4 * 4) * 128 + h * 32 + ql;
#pragma unroll
        for (int r = 0; r < 4; ++r) {
            __builtin_nontemporal_store(olo[r], ob + r * 128);
            __builtin_nontemporal_store(ohi[r], ob + r * 128 + 16);
        }
    }
}

// ---------------- fallback (ws too small): atomic + prep + f32 attn ----------------
__global__ __launch_bounds__(256) void k_reduce_atomic(const float4* __restrict__ k4,
                                                       const float4* __restrict__ v4,
                                                       float* __restrict__ ksum,
                                                       float* __restrict__ vsum) {
    __shared__ float4 stage[2048];
    __shared__ float4 redE[256];
    __shared__ float4 redO[256];
    const int t = threadIdx.x;
    const int b = blockIdx.x;
    const bool isv = (b >= 1024);
    const int bb = b & 1023;
    const float4* __restrict__ src = isv ? v4 : k4;
    float* __restrict__ dst = isv ? vsum : ksum;

    const int wv = t >> 6;
    const int ln = t & 63;
    const long gstart = (long)bb * 8192 + wv * 2048;
    const float4* gsrc = src + gstart + ln;
    char* lbase = (char*)stage + wv * 8192;

#pragma unroll
    for (int j = 0; j < 4; ++j)
        gload_lds16(gsrc + j * 64, lbase + j * 1024);

    float4 z = make_float4(0.f, 0.f, 0.f, 0.f);
    float4 accE = z, accO = z;

#pragma unroll
    for (int c = 0; c < 8; ++c) {
        if (c < 7) {
            const int p1 = (c + 1) & 1;
#pragma unroll
            for (int j = 0; j < 4; ++j)
                gload_lds16(gsrc + (c + 1) * 256 + j * 64,
                            lbase + p1 * 4096 + j * 1024);
            asm volatile("s_waitcnt vmcnt(4)" ::: "memory");
        } else {
            asm volatile("s_waitcnt vmcnt(0)" ::: "memory");
        }
        __builtin_amdgcn_sched_barrier(0);
        const int p = c & 1;
        const float4* lf = (const float4*)(lbase + p * 4096) + ln;
        const float4 x0 = lf[0];
        const float4 x1 = lf[64];
        const float4 x2 = lf[128];
        const float4 x3 = lf[192];
        ADD4(accE, x0); ADD4(accO, x1); ADD4(accE, x2); ADD4(accO, x3);
    }

    redE[wv * 64 + ln] = accE;
    redO[wv * 64 + ln] = accO;
    __syncthreads();

    if (t < 128) {
        const int n0 = t >> 5;
        const int c4 = t & 31;
        const float4* arr = (n0 < 2) ? redE : redO;
        const int base = (n0 & 1) * 32 + c4;
        float4 s = arr[base];
        const float4 s1 = arr[base + 64];
        const float4 s2 = arr[base + 128];
        const float4 s3 = arr[base + 192];
        ADD4(s, s1); ADD4(s, s2); ADD4(s, s3);
        const int n = ((bb >> 1) & 3) * 4 + n0;
        const int c = c4 * 4;
        atomicAdd(&dst[n * 128 + c + 0], s.x);
        atomicAdd(&dst[n * 128 + c + 1], s.y);
        atomicAdd(&dst[n * 128 + c + 2], s.z);
        atomicAdd(&dst[n * 128 + c + 3], s.w);
    }
}

__global__ __launch_bounds__(256) void k_prep(const float* __restrict__ ksum,
                                              const float* __restrict__ vsum,
                                              const float* __restrict__ logit_scale,
                                              float* __restrict__ k2,
                                              float* __restrict__ v2) {
    __shared__ float mk[2048], mv[2048], fac[64];
    const int t = threadIdx.x;
    const float inv = 1.0f / 16384.0f;
    for (int w = t; w < 2048; w += 256) {
        mk[w] = ksum[w] * inv;
        mv[w] = vsum[w] * inv;
    }
    __syncthreads();
    if (t < 64) {
        const int h = t >> 4, n = t & 15;
        float ss = 0.f;
#pragma unroll
        for (int d = 0; d < 32; ++d) {
            float x = mk[n * 128 + h * 32 + d];
            ss += x * x;
        }
        const float nrm = sqrtf(ss);
        const float sc = __expf(fminf(logit_scale[h], 4.6051702f));
        fac[t] = sc / fmaxf(nrm, 1e-12f);
    }
    __syncthreads();
    for (int w = t; w < 2048; w += 256) {
        const int h = w >> 9;
        const int n = (w & 511) >> 5;
        const int d = w & 31;
        const float f = fac[h * 16 + n];
        k2[w] = mk[n * 128 + h * 32 + d] * f;
        v2[w] = mv[n * 128 + h * 32 + d];
    }
}

__global__ __launch_bounds__(256, 2) void k_attn(const float4* __restrict__ q4,
                                                 const float2* __restrict__ mask2,
                                                 const float4* __restrict__ k2f4,
                                                 const float4* __restrict__ v2f4,
                                                 float4* __restrict__ out4) {
    const int t = threadIdx.x;
    const int isub = t >> 5;
    const int l5 = t & 31;
    const int h = l5 >> 3;
    const int g = l5 & 7;

    float4 kreg[16], vreg[16];
#pragma unroll
    for (int n = 0; n < 16; ++n) {
        kreg[n] = k2f4[h * 128 + n * 8 + g];
        vreg[n] = v2f4[h * 128 + n * 8 + g];
    }

    const bool b2 = (g & 4) != 0;
    const bool b1 = (g & 2) != 0;
    const bool b0 = (g & 1) != 0;

    auto process = [&](const float4 qv, const float2 mw) -> float4 {
        float ss = qv.x * qv.x + qv.y * qv.y + qv.z * qv.z + qv.w * qv.w;
        ss += dppf<DPP_XOR1>(ss);
        ss += dppf<DPP_XOR2>(ss);
        ss += dppf<DPP_MIR8>(ss);
        const float rn = rsqrtf(fmaxf(ss, 1e-24f));
        const float qx = qv.x * rn, qy = qv.y * rn, qz = qv.z * rn, qw = qv.w * rn;

        float part[16];
#pragma unroll
        for (int n = 0; n < 16; ++n)
            part[n] = qx * kreg[n].x + qy * kreg[n].y + qz * kreg[n].z + qw * kreg[n].w;

        float r8[8];
#pragma unroll
        for (int j = 0; j < 8; ++j) {
            const float snd = b2 ? part[j] : part[j + 8];
            const float kp  = b2 ? part[j + 8] : part[j];
            r8[j] = kp + dppf<DPP_MIR8>(snd);
        }
        float r4[4];
#pragma unroll
        for (int j = 0; j < 4; ++j) {
            const float snd = b1 ? r8[j] : r8[j + 4];
            const float kp  = b1 ? r8[j + 4] : r8[j];
            r4[j] = kp + dppf<DPP_XOR2>(snd);
        }
        float s0, s1;
        {
            const float sndA = b0 ? r4[0] : r4[2];
            const float kpA  = b0 ? r4[2] : r4[0];
            s0 = kpA + dppf<DPP_XOR1>(sndA);
            const float sndB = b0 ? r4[1] : r4[3];
            const float kpB  = b0 ? r4[3] : r4[1];
            s1 = kpB + dppf<DPP_XOR1>(sndB);
        }

        const float e0 = __expf(s0 + mw.x);
        const float e1 = __expf(s1 + mw.y);

        float ds = e0 + e1;
        ds += dppf<DPP_XOR1>(ds);
        ds += dppf<DPP_XOR2>(ds);
        ds += dppf<DPP_MIR8>(ds);
        const float rden = 1.0f / ds;

        float pf[16];
        pf[0]  = swzf<(0 << 5) | 0x18>(e0);
        pf[1]  = swzf<(0 << 5) | 0x18>(e1);
        pf[2]  = swzf<(1 << 5) | 0x18>(e0);
        pf[3]  = swzf<(1 << 5) | 0x18>(e1);
        pf[4]  = swzf<(2 << 5) | 0x18>(e0);
        pf[5]  = swzf<(2 << 5) | 0x18>(e1);
        pf[6]  = swzf<(3 << 5) | 0x18>(e0);
        pf[7]  = swzf<(3 << 5) | 0x18>(e1);
        pf[8]  = swzf<(4 << 5) | 0x18>(e0);
        pf[9]  = swzf<(4 << 5) | 0x18>(e1);
        pf[10] = swzf<(5 << 5) | 0x18>(e0);
        pf[11] = swzf<(5 << 5) | 0x18>(e1);
        pf[12] = swzf<(6 << 5) | 0x18>(e0);
        pf[13] = swzf<(6 << 5) | 0x18>(e1);
        pf[14] = swzf<(7 << 5) | 0x18>(e0);
        pf[15] = swzf<(7 << 5) | 0x18>(e1);

        float ox = 0.f, oy = 0.f, oz = 0.f, ow = 0.f;
#pragma unroll
        for (int n = 0; n < 16; ++n) {
            ox += pf[n] * vreg[n].x;
            oy += pf[n] * vreg[n].y;
            oz += pf[n] * vreg[n].z;
            ow += pf[n] * vreg[n].w;
        }
        return make_float4(ox * rden, oy * rden, oz * rden, ow * rden);
    };

    int i = blockIdx.x * 128 + isub;
    float4 qA = q4[i * 32 + h * 8 + g];
    float4 qB = q4[(i + 8) * 32 + h * 8 + g];
    float2 mA = mask2[i * 8 + g];
    float2 mB = mask2[(i + 8) * 8 + g];

#pragma unroll 1
    for (int iter = 0; iter < 8; ++iter) {
        const int ip = (iter < 7) ? (i + 16) : i;
        const float4 qA_n = q4[ip * 32 + h * 8 + g];
        const float4 qB_n = q4[(ip + 8) * 32 + h * 8 + g];
        const float2 mA_n = mask2[ip * 8 + g];
        const float2 mB_n = mask2[(ip + 8) * 8 + g];

        const float4 oA = process(qA, mA);
        const float4 oB = process(qB, mB);
        out4[i * 32 + h * 8 + g] = oA;
        out4[(i + 8) * 32 + h * 8 + g] = oB;

        i += 16;
        qA = qA_n; qB = qB_n; mA = mA_n; mB = mB_n;
    }
}

extern "C" void kernel_launch(void* const* d_in, const int* in_sizes, int n_in,
                              void* d_out, int out_size, void* d_ws, size_t ws_size,
                              hipStream_t stream) {
    (void)in_sizes; (void)n_in; (void)out_size;
    const float* q = (const float*)d_in[0];
    const float* k = (const float*)d_in[1];
    const float* v = (const float*)d_in[2];
    const float* mask = (const float*)d_in[5];
    const float* ls = (const float*)d_in[6];

    float* ws = (float*)d_ws;
    float* ksum = ws;
    float* vsum = ws + 2048;
    float* k2b = ws + 4096;    // 1024 floats: packed K2 A-frags
    float* v2b = ws + 5120;    // 2048 floats: packed V B-frags
    float* k2 = ws + 4096;     // fallback f32 (exclusive path)
    float* v2 = ws + 6144;     // fallback f32
    float* part = ws + 8192;   // 131072 float4 = 2MB

    const size_t needed = (size_t)8192 * 4 + (size_t)131072 * 16;
    if (ws_size >= needed) {
        k_reduce_p1<<<1024, 256, 0, stream>>>((const float4*)k, (const float4*)v,
                                              (float4*)part);
        k_finish<<<32, 256, 0, stream>>>((const float4*)part, ls,
                                         (float4*)k2b, v2b);
        k_attn_mfma<<<4096, 256, 0, stream>>>((const float4*)q, (const float4*)mask,
                                              (const float4*)k2b, (const float4*)v2b,
                                              (float*)d_out);
    } else {
        hipMemsetAsync(ws, 0, 4096 * sizeof(float), stream);
        k_reduce_atomic<<<2048, 256, 0, stream>>>((const float4*)k, (const float4*)v,
                                                  ksum, vsum);
        k_prep<<<1, 256, 0, stream>>>(ksum, vsum, ls, k2, v2);
        k_attn<<<2048, 256, 0, stream>>>((const float4*)q, (const float2*)mask,
                                         (const float4*)k2, (const float4*)v2,
                                         (float4*)d_out);
    }
}